// Round 13
// baseline (146.472 us; speedup 1.0000x reference)
//
#include <hip/hip_runtime.h>

namespace {

constexpr int kB  = 16;    // batches
constexpr int kP  = 8;     // pieces
constexpr int kNT = 512;   // time steps (incl. t=0)
constexpr int kNX = 2048;  // cells
constexpr int kW  = 64;    // steps per super-step
constexpr int kChunk = 128;               // cells owned per wave per chunk
constexpr int kNS = 8;                    // super-steps: 7*64 + 63 = 511 rows
constexpr int kNP = 128;                  // blocks: 8 batch-pairs x 16 chunks
// region per chunk = kChunk + 2*kW = 256 cells = 64 lanes x 4 cells
// Each wave advances TWO independent chunks (batches b and b+8, same k):
// two independent dep chains interleave -> fills the solo-wave stall bubbles
// that kept per-step cost at ~400cyc across R7-R12's (null) memory fixes.

// d_ws layout
constexpr size_t kFlagsBytes = (size_t)kNP * kNS * 4;       // 4 KB
constexpr size_t kHaloOff    = 32768;  // float halo[kNP][kNS][2][kChunk] (f32 bits)

// Cross-lane shift by one lane via DPP (VALU; no LDS round-trip).
__device__ __forceinline__ float dpp_shr1(float x) {
    return __builtin_bit_cast(float,
        __builtin_amdgcn_update_dpp(0, __builtin_bit_cast(int, x), 0x138, 0xF, 0xF, true));
}
__device__ __forceinline__ float dpp_shl1(float x) {
    return __builtin_bit_cast(float,
        __builtin_amdgcn_update_dpp(0, __builtin_bit_cast(int, x), 0x130, 0xF, 0xF, true));
}

__device__ __forceinline__ float fpar(float u) {  // f(u) = u - u^2
    return __builtin_fmaf(-u, u, u);
}

// Relaxed agent-scope RMWs (coherence-point ops, no cache maintenance).
__device__ __forceinline__ void mall_store(int* p, float v) {
    (void)__hip_atomic_exchange(p, __builtin_bit_cast(int, v),
                                __ATOMIC_RELAXED, __HIP_MEMORY_SCOPE_AGENT);
}
__device__ __forceinline__ float mall_load(int* p) {
    return __builtin_bit_cast(float,
        __hip_atomic_fetch_add(p, 0, __ATOMIC_RELAXED, __HIP_MEMORY_SCOPE_AGENT));
}

__global__ __launch_bounds__(64)
void godunov_dual(const float* __restrict__ xs,   // (B, P+1)
                  const float* __restrict__ ks,   // (B, P)
                  const int*   __restrict__ pm,   // (B, P)
                  const float* __restrict__ dxp,  // (B,)
                  const float* __restrict__ dtp,  // (B,)
                  float* __restrict__ out,        // (B,1,NT,NX) fp32
                  int*   __restrict__ flags,      // [kNP][kNS], pre-zeroed
                  int*   __restrict__ halo)       // [kNP][kNS][2][kChunk]
{
    // All 64 lanes stage unconditionally (no per-step exec-mask dance, static
    // ds offsets); flush pulls only the owned 128 cells per row.
    __shared__ float rowbuf[2][16][4 * 64];   // 32 KB

    const int p    = blockIdx.x;      // 0..127
    const int bp   = p >> 4;          // batch pair: batches bp and bp+8
    const int k    = p & 15;          // chunk within batch
    const int bA   = bp;
    const int bB   = bp + 8;
    const int lane = threadIdx.x;     // 0..63, one wave per block
    const int rs   = k * kChunk - kW; // region start (may be <0)
    const int gi0  = rs + 4 * lane;   // this lane's first cell

    const float dxv = dxp[0];
    const float lam = dtp[0] / dxv;

    // ---- piecewise-constant IC parameters, both batches ----
    float bndsA[kP], bndsB[kP];
    int npA = 0, npB = 0;
#pragma unroll
    for (int j = 0; j < kP; ++j) {
        int mA = pm[bA * kP + j];
        int mB = pm[bB * kP + j];
        npA += mA; npB += mB;
        bndsA[j] = mA ? xs[bA * (kP + 1) + j + 1] : __builtin_inff();
        bndsB[j] = mB ? xs[bB * (kP + 1) + j + 1] : __builtin_inff();
    }
    const int capA = npA - 1, capB = npB - 1;

    auto icvalA = [&](int gi) -> float {
        float xc = ((float)gi + 0.5f) * dxv;
        int idx = 0;
#pragma unroll
        for (int j = 0; j < kP; ++j) idx += (xc >= bndsA[j]) ? 1 : 0;
        return ks[bA * kP + min(idx, capA)];
    };
    auto icvalB = [&](int gi) -> float {
        float xc = ((float)gi + 0.5f) * dxv;
        int idx = 0;
#pragma unroll
        for (int j = 0; j < kP; ++j) idx += (xc >= bndsB[j]) ? 1 : 0;
        return ks[bB * kP + min(idx, capB)];
    };

    // Constant ghost values (frozen IC endpoints), per batch.
    const float gLA = icvalA(0), gRA = icvalA(kNX - 1);
    const float gLB = icvalB(0), gRB = icvalB(kNX - 1);

    // Region geometry identical for both chunks (same k).
    const bool  laneIn  = (gi0 >= 0) && (gi0 < kNX);
    const float gvA     = (gi0 < 0) ? gLA : gRA;
    const float gvB     = (gi0 < 0) ? gLB : gRB;
    const bool  edgeBlk = (k == 0) || (k == 15);

    // ---- seed at t=0 from IC ----
    float uA[4], uB[4];
#pragma unroll
    for (int c = 0; c < 4; ++c) {
        uA[c] = laneIn ? icvalA(gi0 + c) : gvA;
        uB[c] = laneIn ? icvalB(gi0 + c) : gvB;
    }

    // Lanes 16..47 own the chunk (cells k*128 .. k*128+127).
    const bool writer = (lane >= 16) && (lane < 48);
    if (writer) {   // row 0 = IC, off the hot loop
        float* p0A = out + ((size_t)bA * kNT) * kNX;
        float* p0B = out + ((size_t)bB * kNT) * kNX;
        *reinterpret_cast<float4*>(p0A + gi0) = make_float4(uA[0], uA[1], uA[2], uA[3]);
        *reinterpret_cast<float4*>(p0B + gi0) = make_float4(uB[0], uB[1], uB[2], uB[3]);
    }

    const int colh = (lane & 31) * 4;   // flush column within chunk (floats)
    const int half = lane >> 5;         // flush row parity
    int trow = 1;                       // next output row

    // One step for one 4-cell system; the A/B calls are independent -> ILP.
    auto step1 = [&](float (&u)[4], float gvv) {
        float um = dpp_shr1(u[3]);
        float up = dpp_shl1(u[0]);
        // Godunov flux, branchless concave form:
        //   F(uL,uR) = min( f(min(uL,1/2)), f(max(uR,1/2)) )
        float fl[4], fh[4];
#pragma unroll
        for (int c = 0; c < 4; ++c) {
            fl[c] = fpar(fminf(u[c], 0.5f));
            fh[c] = fpar(fmaxf(u[c], 0.5f));
        }
        float flm = fpar(fminf(um, 0.5f));
        float fhp = fpar(fmaxf(up, 0.5f));
        float F0 = fminf(flm,   fh[0]);
        float F1 = fminf(fl[0], fh[1]);
        float F2 = fminf(fl[1], fh[2]);
        float F3 = fminf(fl[2], fh[3]);
        float F4 = fminf(fl[3], fhp);
        u[0] = __builtin_fmaf(-lam, F1 - F0, u[0]);
        u[1] = __builtin_fmaf(-lam, F2 - F1, u[1]);
        u[2] = __builtin_fmaf(-lam, F3 - F2, u[2]);
        u[3] = __builtin_fmaf(-lam, F4 - F3, u[3]);
        if (edgeBlk) {   // wave-uniform; skipped by 14/16 blocks
#pragma unroll
            for (int c = 0; c < 4; ++c) u[c] = laneIn ? u[c] : gvv;
        }
    };

    auto stage = [&](int q) {   // unconditional, static offsets, no exec mask
        *reinterpret_cast<float4*>(&rowbuf[0][q][lane * 4]) =
            make_float4(uA[0], uA[1], uA[2], uA[3]);
        *reinterpret_cast<float4*>(&rowbuf[1][q][lane * 4]) =
            make_float4(uB[0], uB[1], uB[2], uB[3]);
    };

    auto flush = [&](int nrows) {  // owned cells sit at region offsets 64..191
        float* gbA = out + ((size_t)bA * kNT + trow) * kNX + k * kChunk + colh;
        float* gbB = out + ((size_t)bB * kNT + trow) * kNX + k * kChunk + colh;
#pragma unroll
        for (int i = 0; i < 8; ++i) {
            int r = 2 * i + half;
            if (r < nrows) {
                float4 vA = *reinterpret_cast<const float4*>(&rowbuf[0][r][64 + colh]);
                *reinterpret_cast<float4*>(gbA + (size_t)r * kNX) = vA;
                float4 vB = *reinterpret_cast<const float4*>(&rowbuf[1][r][64 + colh]);
                *reinterpret_cast<float4*>(gbB + (size_t)r * kNX) = vB;
            }
        }
        trow += nrows;
    };

#pragma unroll 1
    for (int s = 0; s < kNS; ++s) {
        // ---- re-seed halo lanes from neighbor blocks (state at 64*s) ----
        if (s > 0) {
            const bool needL = (k > 0), needR = (k < 15);
            if (lane == 0) {   // lane-0-only poll; whole wave waits on branch
                int* fL = flags + (p - 1) * kNS + s;
                int* fR = flags + (p + 1) * kNS + s;
                int okL = needL ? 0 : 1, okR = needR ? 0 : 1;
                for (int it = 0; it < (1 << 22); ++it) {
                    if (!okL) okL = __hip_atomic_fetch_add(fL, 0, __ATOMIC_RELAXED,
                                                           __HIP_MEMORY_SCOPE_AGENT);
                    if (!okR) okR = __hip_atomic_fetch_add(fR, 0, __ATOMIC_RELAXED,
                                                           __HIP_MEMORY_SCOPE_AGENT);
                    if (okL && okR) break;
                    __builtin_amdgcn_s_sleep(4);
                }
            }
            asm volatile("" ::: "memory");   // keep data reads below the spin

            if (lane < 16) {
                if (needL) {  // left neighbor's cells 64..127, both chunks
                    int* hp = halo + (((size_t)(p - 1) * kNS + s) * 2) * kChunk
                            + 64 + 4 * lane;
#pragma unroll
                    for (int c = 0; c < 4; ++c) uA[c] = mall_load(hp + c);
                    hp += kChunk;
#pragma unroll
                    for (int c = 0; c < 4; ++c) uB[c] = mall_load(hp + c);
                }  // k==0: stays pinned at gL
            } else if (lane >= 48) {
                if (needR) {  // right neighbor's cells 0..63, both chunks
                    int* hp = halo + (((size_t)(p + 1) * kNS + s) * 2) * kChunk
                            + 4 * (lane - 48);
#pragma unroll
                    for (int c = 0; c < 4; ++c) uA[c] = mall_load(hp + c);
                    hp += kChunk;
#pragma unroll
                    for (int c = 0; c < 4; ++c) uB[c] = mall_load(hp + c);
                }  // k==15: stays pinned at gR
            }
            // lanes 16..47 keep their registers (own chunks, still valid)
        }

        // ---- 64 steps (last super-step: 63), staged, flushed by 16 ----
        const int ngroups = (s == kNS - 1) ? 3 : 4;
#pragma unroll 1
        for (int g = 0; g < ngroups; ++g) {
#pragma unroll
            for (int q = 0; q < 16; ++q) {
                step1(uA, gvA);
                step1(uB, gvB);
                stage(q);
            }
            flush(16);
        }
        if (s == kNS - 1) {   // tail 15 steps -> rows 497..511
#pragma unroll
            for (int q = 0; q < 15; ++q) {
                step1(uA, gvA);
                step1(uB, gvB);
                stage(q);
            }
            flush(15);
        }

        // ---- publish own chunk states (time 64*(s+1)) + one flag ----
        if (s < kNS - 1) {
            if (writer) {
                int* hp = halo + (((size_t)p * kNS + (s + 1)) * 2) * kChunk
                        + 4 * (lane - 16);
#pragma unroll
                for (int c = 0; c < 4; ++c) mall_store(hp + c, uA[c]);
                hp += kChunk;
#pragma unroll
                for (int c = 0; c < 4; ++c) mall_store(hp + c, uB[c]);
            }
            asm volatile("s_waitcnt vmcnt(0)" ::: "memory");  // data before flag
            if (lane == 0)
                (void)__hip_atomic_exchange(flags + p * kNS + (s + 1), 1,
                                            __ATOMIC_RELAXED, __HIP_MEMORY_SCOPE_AGENT);
        }
    }
}

}  // namespace

extern "C" void kernel_launch(void* const* d_in, const int* in_sizes, int n_in,
                              void* d_out, int out_size, void* d_ws, size_t ws_size,
                              hipStream_t stream) {
    const float* xs  = (const float*)d_in[0];
    const float* ks  = (const float*)d_in[1];
    const int*   pm  = (const int*)d_in[2];
    const float* dxv = (const float*)d_in[3];
    const float* dtv = (const float*)d_in[4];
    // d_in[5] = t_coords: only carries the (NT, NX) shape; values unused.
    float* out = (float*)d_out;

    int* flags = (int*)d_ws;
    int* halo  = (int*)((char*)d_ws + kHaloOff);

    // Flags must be zeroed every call (d_ws is not re-poisoned between replays).
    hipMemsetAsync(flags, 0, kFlagsBytes, stream);

    hipLaunchKernelGGL(godunov_dual, dim3(kNP), dim3(64), 0, stream,
                       xs, ks, pm, dxv, dtv, out, flags, halo);
}

// Round 14
// 89.128 us; speedup vs baseline: 1.6434x; 1.6434x over previous
//
#include <hip/hip_runtime.h>

namespace {

constexpr int kB  = 16;    // batches
constexpr int kP  = 8;     // pieces
constexpr int kNT = 512;   // time steps (incl. t=0)
constexpr int kNX = 2048;  // cells
constexpr int kNS = 8;     // supersteps of 64 steps (last: 63)
constexpr int kBlocks = 256;               // 16 batches x 16 chunks of 128 cells
constexpr size_t kFlagsBytes = (size_t)kBlocks * kNS * 4;   // 8 KB
constexpr size_t kHaloOff    = 32768;      // float halo[256][8][128] = 1 MB

// Cross-lane shift by one lane via DPP (VALU; no LDS round-trip).
__device__ __forceinline__ float dpp_shr1(float x) {
    return __builtin_bit_cast(float,
        __builtin_amdgcn_update_dpp(0, __builtin_bit_cast(int, x), 0x138, 0xF, 0xF, true));
}
__device__ __forceinline__ float dpp_shl1(float x) {
    return __builtin_bit_cast(float,
        __builtin_amdgcn_update_dpp(0, __builtin_bit_cast(int, x), 0x130, 0xF, 0xF, true));
}

__device__ __forceinline__ float fpar(float u) {  // f(u) = u - u^2
    return __builtin_fmaf(-u, u, u);
}

// Relaxed agent-scope RMWs (coherence-point ops, no cache maintenance).
__device__ __forceinline__ void mall_store(int* p, float v) {
    (void)__hip_atomic_exchange(p, __builtin_bit_cast(int, v),
                                __ATOMIC_RELAXED, __HIP_MEMORY_SCOPE_AGENT);
}
__device__ __forceinline__ float mall_load(int* p) {
    return __builtin_bit_cast(float,
        __hip_atomic_fetch_add(p, 0, __ATOMIC_RELAXED, __HIP_MEMORY_SCOPE_AGENT));
}

// Raw barrier: only LDS ordering needed (global stores are private).
__device__ __forceinline__ void block_barrier() {
    asm volatile("s_waitcnt lgkmcnt(0)" ::: "memory");
    __builtin_amdgcn_s_barrier();
    __builtin_amdgcn_sched_barrier(0);
    asm volatile("" ::: "memory");
}

// 3 waves/block, 2 cells/lane, overlapping 128-cell windows over a 256-cell
// block region (owned cells [64,192) in region coords = global [k*128,+128)).
// half 0 windows: [0,128), [64,192), [128,256); after 32 steps valid centers
// [32,96),[96,160),[160,224) tile the eroded region -> LDS exchange rebuilds
// half-1 windows [32,160), [96,224) (wave 2 idles). No sync within a half:
// the per-wave issue cadence (~7cyc/instr, R13) makes per-step wall time =
// instr count on ONE wave; splitting 35 instr across 3 waves is the win.
__global__ __launch_bounds__(192)
void godunov_tri(const float* __restrict__ xs,   // (B, P+1)
                 const float* __restrict__ ks,   // (B, P)
                 const int*   __restrict__ pmk,  // (B, P)
                 const float* __restrict__ dxp,  // (B,)
                 const float* __restrict__ dtp,  // (B,)
                 float* __restrict__ out,        // (B,1,NT,NX) fp32
                 int*   __restrict__ flags,      // [256][kNS], pre-zeroed
                 int*   __restrict__ halo)       // [256][kNS][128] f32 bits
{
    __shared__ float rowbuf[2][16][128];   // 16 KB, double-buffered by group
    __shared__ float regionBuf[256];       // 1 KB, exchange/rebuild staging

    const int p    = blockIdx.x;
    const int b    = p >> 4;
    const int k    = p & 15;
    const int tid  = threadIdx.x;
    const int wid  = tid >> 6;     // wave 0..2
    const int lane = tid & 63;
    const int rs   = k * 128 - 64; // global cell at region offset 0

    const float dxv = dxp[0];
    const float lam = dtp[0] / dxv;

    // ---- piecewise-constant IC parameters ----
    int np = 0;
    float bnds[kP];
#pragma unroll
    for (int j = 0; j < kP; ++j) {
        int m = pmk[b * kP + j];
        np += m;
        bnds[j] = m ? xs[b * (kP + 1) + j + 1] : __builtin_inff();
    }
    const int cap = np - 1;

    auto icval = [&](int gi) -> float {   // gi<0 -> gL, gi>=kNX -> gR (xc clamps)
        float xc = ((float)gi + 0.5f) * dxv;
        int idx = 0;
#pragma unroll
        for (int j = 0; j < kP; ++j) idx += (xc >= bnds[j]) ? 1 : 0;
        return ks[b * kP + min(idx, cap)];
    };

    const float gL = icval(0);
    const float gR = icval(kNX - 1);
    const bool  edgeBlk = (k == 0) || (k == 15);

    // ---- window state (per wave, recomputed per half) ----
    int wb = 0, cbase = 0, slo = 0, shi = 0;
    bool act = true;
    float pm0 = 1.f, pa0 = 0.f, pm1 = 1.f, pa1 = 0.f;

    auto setwin = [&](int half) {
        if (half == 0) {
            wb = 64 * wid; act = true;
            if (wid == 0)      { cbase = -64; slo = 32; shi = 48; }
            else if (wid == 1) { cbase =   0; slo = 16; shi = 48; }
            else               { cbase =  64; slo = 16; shi = 32; }
        } else {
            act = (wid < 2);
            wb = 32 + 64 * wid; cbase = -32 + 64 * wid; slo = 16; shi = 48;
        }
        // pin masks for domain ghosts (cells -1 / kNX), edge blocks only
        pm0 = 1.f; pa0 = 0.f; pm1 = 1.f; pa1 = 0.f;
        if (edgeBlk && act) {
            int g0 = rs + wb + 2 * lane, g1 = g0 + 1;
            if (g0 == -1 || g0 == kNX) { pm0 = 0.f; pa0 = (g0 == -1) ? gL : gR; }
            if (g1 == -1 || g1 == kNX) { pm1 = 0.f; pa1 = (g1 == -1) ? gL : gR; }
        }
    };

    float u0, u1;

    auto do_step = [&]() {
        float fl0 = fpar(fminf(u0, 0.5f)), fh0 = fpar(fmaxf(u0, 0.5f));
        float fl1 = fpar(fminf(u1, 0.5f)), fh1 = fpar(fmaxf(u1, 0.5f));
        float flm = dpp_shr1(fl1);            // left lane's fl of its 2nd cell
        float F0  = fminf(flm, fh0);          // flux at left face of cell0
        float F1  = fminf(fl0, fh1);          // flux between cell0, cell1
        float F2  = dpp_shl1(F0);             // right lane's F0 = right face of cell1
        u0 = __builtin_fmaf(-lam, F1 - F0, u0);
        u1 = __builtin_fmaf(-lam, F2 - F1, u1);
        if (edgeBlk) {                        // wave-uniform; 14/16 blocks skip
            u0 = __builtin_fmaf(u0, pm0, pa0);
            u1 = __builtin_fmaf(u1, pm1, pa1);
        }
    };

    int trow = 1, gp = 0;

    // one group: n steps (n<=16), stage assigned owned cells, barrier, flush
    auto group = [&](int n) {
#pragma unroll
        for (int q = 0; q < 16; ++q) {
            if (q < n && act) {
                do_step();
                if (lane >= slo && lane < shi)
                    *reinterpret_cast<float2*>(&rowbuf[gp][q][cbase + 2 * lane]) =
                        make_float2(u0, u1);
            }
        }
        block_barrier();   // all stages visible before cross-wave flush reads
        for (int r = wid; r < n; r += 3) {
            float2 v = *reinterpret_cast<const float2*>(&rowbuf[gp][r][2 * lane]);
            float* dst = out + ((size_t)b * kNT + trow + r) * kNX + k * 128 + 2 * lane;
            *reinterpret_cast<float2*>(dst) = v;
        }
        trow += n; gp ^= 1;   // double-buffer: no post-flush barrier needed
    };

    // ---- seed superstep 0 from IC; store row 0 ----
    setwin(0);
    u0 = icval(rs + wb + 2 * lane);
    u1 = icval(rs + wb + 2 * lane + 1);
    if (lane >= slo && lane < shi) {
        float* dst = out + ((size_t)b * kNT) * kNX + k * 128 + cbase + 2 * lane;
        *reinterpret_cast<float2*>(dst) = make_float2(u0, u1);
    }

#pragma unroll 1
    for (int s = 0; s < kNS; ++s) {
        if (s > 0) {   // rebuild half-0 windows from regionBuf (filled at s-1 end)
            setwin(0);
            float2 w = *reinterpret_cast<const float2*>(&regionBuf[wb + 2 * lane]);
            u0 = w.x; u1 = w.y;
        }

        group(16); group(16);   // half 0: 32 steps

        // intra-block exchange at tau=32: write central-valid 64, rebuild windows
        if (lane >= 16 && lane < 48)
            *reinterpret_cast<float2*>(&regionBuf[wb + 2 * lane]) = make_float2(u0, u1);
        block_barrier();
        setwin(1);
        if (act) {
            float2 w = *reinterpret_cast<const float2*>(&regionBuf[wb + 2 * lane]);
            u0 = w.x; u1 = w.y;
        }

        group(16); group(s == kNS - 1 ? 15 : 16);   // half 1: 32 (last: 31)

        if (s < kNS - 1) {
            // publish owned 128 (centrals of w0/w1) + write regionBuf centrals
            if (act && lane >= 16 && lane < 48) {
                *reinterpret_cast<float2*>(&regionBuf[wb + 2 * lane]) =
                    make_float2(u0, u1);
                int* hp = halo + ((size_t)p * kNS + (s + 1)) * 128 + (wb + 2 * lane - 64);
                mall_store(hp, u0); mall_store(hp + 1, u1);
            }
            asm volatile("s_waitcnt vmcnt(0)" ::: "memory");  // data before flag
            block_barrier();   // barrier1: publishes done (each wave drained)
            if (wid == 0 && lane == 0) {
                (void)__hip_atomic_exchange(flags + p * kNS + (s + 1), 1,
                                            __ATOMIC_RELAXED, __HIP_MEMORY_SCOPE_AGENT);
                int okL = (k > 0) ? 0 : 1, okR = (k < 15) ? 0 : 1;
                int* fL = flags + (p - 1) * kNS + (s + 1);
                int* fR = flags + (p + 1) * kNS + (s + 1);
                for (int it = 0; it < (1 << 22); ++it) {
                    if (!okL) okL = __hip_atomic_fetch_add(fL, 0, __ATOMIC_RELAXED,
                                                           __HIP_MEMORY_SCOPE_AGENT);
                    if (!okR) okR = __hip_atomic_fetch_add(fR, 0, __ATOMIC_RELAXED,
                                                           __HIP_MEMORY_SCOPE_AGENT);
                    if (okL && okR) break;
                    __builtin_amdgcn_s_sleep(4);
                }
            }
            block_barrier();   // barrier2: spin done
            if (wid == 2) {    // fill region ends [0,64) and [192,256)
                if (lane < 32) {
                    float a, c;
                    if (k > 0) {
                        int* hp = halo + ((size_t)(p - 1) * kNS + (s + 1)) * 128 + 64 + 2 * lane;
                        a = mall_load(hp); c = mall_load(hp + 1);
                    } else { a = gL; c = gL; }
                    *reinterpret_cast<float2*>(&regionBuf[2 * lane]) = make_float2(a, c);
                } else {
                    int l2 = lane - 32;
                    float a, c;
                    if (k < 15) {
                        int* hp = halo + ((size_t)(p + 1) * kNS + (s + 1)) * 128 + 2 * l2;
                        a = mall_load(hp); c = mall_load(hp + 1);
                    } else { a = gR; c = gR; }
                    *reinterpret_cast<float2*>(&regionBuf[192 + 2 * l2]) = make_float2(a, c);
                }
            }
            block_barrier();   // barrier3: regionBuf [0,256) complete
        }
    }
}

}  // namespace

extern "C" void kernel_launch(void* const* d_in, const int* in_sizes, int n_in,
                              void* d_out, int out_size, void* d_ws, size_t ws_size,
                              hipStream_t stream) {
    const float* xs  = (const float*)d_in[0];
    const float* ks  = (const float*)d_in[1];
    const int*   pmk = (const int*)d_in[2];
    const float* dxv = (const float*)d_in[3];
    const float* dtv = (const float*)d_in[4];
    // d_in[5] = t_coords: only carries the (NT, NX) shape; values unused.
    float* out = (float*)d_out;

    int* flags = (int*)d_ws;
    int* halo  = (int*)((char*)d_ws + kHaloOff);

    // Flags must be zeroed every call (d_ws is not re-poisoned between replays).
    hipMemsetAsync(flags, 0, kFlagsBytes, stream);

    hipLaunchKernelGGL(godunov_tri, dim3(kBlocks), dim3(192), 0, stream,
                       xs, ks, pmk, dxv, dtv, out, flags, halo);
}